// Round 6
// baseline (124.148 us; speedup 1.0000x reference)
//
#include <hip/hip_runtime.h>
#include <hip/hip_bf16.h>

#define NPIX 4096
#define NCH  256

typedef __attribute__((ext_vector_type(8))) short short8;
typedef __attribute__((ext_vector_type(16))) float f32x16;
typedef __attribute__((ext_vector_type(8))) int i32x8;

// 4x 8-byte k-chunks -> one K=64 f8f6f4 operand (8 VGPRs)
union Frag64 { long l[4]; i32x8 v; };

#define SC1 0x7F7F7F7F  // E8M0 scale bytes = 127 -> scale 1.0 (all blocks)

// pack 4 f32 -> 4 fp8 e4m3 bytes (OCP on gfx950), byte0=a .. byte3=d
__device__ inline unsigned int pkfp8x4(float a, float b, float c, float d) {
    int w = __builtin_amdgcn_cvt_pk_fp8_f32(a, b, 0, false);
    w = __builtin_amdgcn_cvt_pk_fp8_f32(c, d, w, true);
    return (unsigned int)w;
}

__device__ inline unsigned char fp8b(float a) {
    return (unsigned char)(__builtin_amdgcn_cvt_pk_fp8_f32(a, a, 0, false) & 0xff);
}

__device__ inline float bperm(int srclane, float v) {
    return __int_as_float(__builtin_amdgcn_ds_bpermute(
        srclane << 2, __float_as_int(v)));
}

// exp2 8 score values -> 8 fp8 bytes of the PV A-frag (in-register, no LDS).
// Rows r of a 32x32 MFMA C are (r&3)+8*(r>>2)+4*hi; X covers rows off..off+3,
// Y rows off+4..off+7 (+4*hi). permlane32_swap exchanges X's hi-half with
// Y's lo-half so (Y<<32)|X holds 8 consecutive m-bytes per lane half —
// exactly the K=64 MFMA A-operand granule. Verified end-to-end in r3.
// Transients kept to 8 floats (r3's e[16] arrays caused the spill).
__device__ inline long packhalf(const f32x16& s, int off, float& psum) {
    float e0 = __builtin_exp2f(s[off + 0]);
    float e1 = __builtin_exp2f(s[off + 1]);
    float e2 = __builtin_exp2f(s[off + 2]);
    float e3 = __builtin_exp2f(s[off + 3]);
    unsigned int X = pkfp8x4(e0, e1, e2, e3);
    float f0 = __builtin_exp2f(s[off + 4]);
    float f1 = __builtin_exp2f(s[off + 5]);
    float f2 = __builtin_exp2f(s[off + 6]);
    float f3 = __builtin_exp2f(s[off + 7]);
    unsigned int Y = pkfp8x4(f0, f1, f2, f3);
    psum += ((e0 + e1) + (e2 + e3)) + ((f0 + f1) + (f2 + f3));
    asm("v_permlane32_swap_b32 %0, %1" : "+v"(X), "+v"(Y));
    return (long)(((unsigned long)Y << 32) | X);
}

// ---------------------------------------------------------------------------
// Kernel A (merged): blocks [0,1024): x transpose+bf16; [1024,1344): weights.
//   x -> XT [B][4096][256] bf16;  w -> Wc [320][256] bf16 (+bc f32[320]).
//   K-side rows get 1/sqrt(32)*log2(e) folded in (softmax runs in exp2).
// ---------------------------------------------------------------------------
__global__ void __launch_bounds__(256) prep_kernel(
    const float* __restrict__ x,
    const float* __restrict__ wq, const float* __restrict__ bq,
    const float* __restrict__ wk, const float* __restrict__ bk,
    const float* __restrict__ wv, const float* __restrict__ bv,
    __hip_bfloat16* __restrict__ Wc, float* __restrict__ bc,
    __hip_bfloat16* __restrict__ XTg)
{
    const int bid = blockIdx.x;
    const int t   = threadIdx.x;
    if (bid >= 1024) {
        const int j = bid - 1024;
        const float kQ = 0.17677669529663687f * 1.4426950408889634f;
        const float* src;
        float sc = 1.0f;
        if (j < 32)       { src = wq + j * 256; }
        else if (j < 64)  { src = wk + (j - 32) * 256; sc = kQ; }
        else              { src = wv + (j - 64) * 256; }
        Wc[j * 256 + t] = __float2bfloat16(src[t] * sc);
        if (t == 0) {
            float bb = (j < 32) ? bq[j] : (j < 64) ? bk[j - 32] * kQ : bv[j - 64];
            bc[j] = bb;
        }
        return;
    }
    __shared__ float xs[64][65];
    const int b  = bid >> 8;
    const int c0 = ((bid >> 6) & 3) * 64;
    const int n0 = (bid & 63) * 64;
    const float* xb = x + ((size_t)b * NCH + c0) * NPIX + n0;
    #pragma unroll 4
    for (int i = 0; i < 16; ++i) {
        int c = i * 4 + (t >> 6);
        int n = t & 63;
        xs[c][n] = xb[(size_t)c * NPIX + n];
    }
    __syncthreads();
    #pragma unroll 4
    for (int i = 0; i < 16; ++i) {
        int nn = i * 4 + (t >> 6);
        int cL = t & 63;
        XTg[((size_t)b * NPIX + n0 + nn) * NCH + c0 + cL] =
            __float2bfloat16(xs[cL][nn]);
    }
}

// ---------------------------------------------------------------------------
// Kernel C: QKV projection via MFMA 32x32x16 bf16; OUTPUTS IN FP8 e4m3.
//   Q8,K8: [B][n][32] fp8 (K pre-scaled by 1/sqrt32*log2e).
//   V8 : frag-native [B][n/16][c=256][n%16] fp8 -> 8B/lane PV B-frags.
// grid (32, 2, B) — 256 blocks (1/CU).
// ---------------------------------------------------------------------------
__global__ void __launch_bounds__(256) proj_kernel(
    const __hip_bfloat16* __restrict__ Wc, const float* __restrict__ bc,
    const __hip_bfloat16* __restrict__ XTg,
    unsigned char* __restrict__ Q8, unsigned char* __restrict__ K8,
    unsigned char* __restrict__ V8)
{
    const int b    = blockIdx.z;
    const int t    = threadIdx.x;
    const int lane = t & 63;
    const int wid  = t >> 6;
    const int lo   = lane & 31;
    const int hi   = lane >> 5;
    const int n0   = blockIdx.x * 128 + wid * 32;
    const int jb   = blockIdx.y * 5;

    short8 xf[16];
    const __hip_bfloat16* xr = XTg + ((size_t)b * NPIX + n0 + lo) * NCH;
    #pragma unroll
    for (int ks = 0; ks < 16; ++ks)
        xf[ks] = *(const short8*)(xr + ks * 16 + hi * 8);

    for (int jo = 0; jo < 5; ++jo) {
        const int jt = jb + jo;
        f32x16 acc;
        #pragma unroll
        for (int r = 0; r < 16; ++r) acc[r] = 0.f;
        const __hip_bfloat16* wr = Wc + (size_t)(jt * 32 + lo) * NCH;
        #pragma unroll
        for (int ks = 0; ks < 16; ++ks) {
            short8 wf = *(const short8*)(wr + ks * 16 + hi * 8);
            acc = __builtin_amdgcn_mfma_f32_32x32x16_bf16(wf, xf[ks], acc, 0, 0, 0);
        }
        if (jt < 2) {
            unsigned char* dst = (jt == 0 ? Q8 : K8)
                               + ((size_t)b * NPIX + n0 + lo) * 32;
            #pragma unroll
            for (int g = 0; g < 4; ++g) {
                int jr = 8 * g + 4 * hi;
                unsigned int w = pkfp8x4(acc[4 * g + 0] + bc[jt * 32 + jr + 0],
                                         acc[4 * g + 1] + bc[jt * 32 + jr + 1],
                                         acc[4 * g + 2] + bc[jt * 32 + jr + 2],
                                         acc[4 * g + 3] + bc[jt * 32 + jr + 3]);
                *(unsigned int*)(dst + jr) = w;
            }
        } else {
            unsigned char* vb = V8 + (size_t)b * NPIX * NCH
                              + (size_t)((n0 + lo) >> 4) * 4096 + (lo & 15);
            #pragma unroll
            for (int r = 0; r < 16; ++r) {
                int jr = (r & 3) + 8 * (r >> 2) + 4 * hi;
                int c  = jt * 32 + jr - 64;
                vb[(size_t)c * 16] = fp8b(acc[r] + bc[jt * 32 + jr]);
            }
        }
    }
}

// ---------------------------------------------------------------------------
// Kernel D v4: BARRIER-FREE attention + residual + LayerNorm (r3 structure,
// spill fixed). Block = 32-q tile, 4 waves (256 thr), grid (128,4).
// Wave (mw,cw) = (wid>>1, wid&1): owns m-range [mw*2048, +2048) (32 chunks
// of 64 m) AND c-range [cw*128, +128). QK+exp duplicated across cw (cheap:
// PV dominates MFMA 2:1); acc = 4 x f32x16 = 64 VGPR (r3's 128 caused the
// spill disaster). P built fully in-register: exp2 -> cvt_pk_fp8 ->
// v_permlane32_swap (verified in r3). NO LDS / NO barriers in main loop.
// launch_bounds(256,3): VGPR cap 168, ~3 waves/SIMD, no spill (predicted
// demand ~150). Epilogue: ds atomicAdd O-combine + LN (r3-verified).
// ---------------------------------------------------------------------------
__global__ void __launch_bounds__(256, 3) attn_kernel(
    const unsigned char* __restrict__ Q8, const unsigned char* __restrict__ K8,
    const unsigned char* __restrict__ V8, const __hip_bfloat16* __restrict__ XTg,
    const float* __restrict__ gamma_p, const float* __restrict__ lnw,
    const float* __restrict__ lnb, float* __restrict__ out)
{
    // [0,32768): obuf [32 q][256 c] f32 (reduction target)
    // [0,37888): ybuf [256][37] f32 (epilogue overlay of obuf)
    // [37888,38144): red_s [2 mw][32 q]
    // [38144,39168): red2 [32 q][4 w][2]
    __shared__ char smem[39168];

    const int t    = threadIdx.x;
    const int lane = t & 63;
    const int wid  = t >> 6;          // 0..3
    const int lo   = lane & 31;
    const int hi   = lane >> 5;
    const int mw   = wid >> 1;        // m-range owner (0..1)
    const int cw   = wid & 1;         // c-range owner (0..1)

    // XCD-aware swizzle: batch b pinned to XCDs {2b, 2b+1}
    const int lid = blockIdx.y * 128 + blockIdx.x;
    const int xcd = lid & 7;
    const int b   = xcd >> 1;
    const int q0  = ((xcd & 1) * 64 + (lid >> 3)) * 32;

    // zero obuf (epilogue-only dependency)
    float4* ob4 = (float4*)smem;
    float4 zz; zz.x = 0.f; zz.y = 0.f; zz.z = 0.f; zz.w = 0.f;
    #pragma unroll
    for (int i = 0; i < 8; ++i) ob4[t + 256 * i] = zz;

    // Q B-frags (32x32x16): col q=lo, k-byte = hi*8+j; two d-halves
    const unsigned char* Qb = Q8 + ((size_t)b * NPIX + q0) * 32;
    const long qf0 = *(const long*)(Qb + lo * 32 + hi * 8);
    const long qf1 = *(const long*)(Qb + lo * 32 + 16 + hi * 8);

    // wave's K rows: m = mw*2048 + ch*64 + half*32 + lo
    const unsigned char* Kw = K8 + (size_t)b * NPIX * 32
                            + ((size_t)mw * 2048 + lo) * 32 + hi * 8;
    // wave's V stream: c = cw*128 + cb*32 + lo; m-subtile stride 4096 B
    const unsigned char* Vw = V8 + (size_t)b * NPIX * NCH
                            + (size_t)(mw * 128) * 4096
                            + (size_t)(cw * 128 + lo) * 16 + hi * 8;

    f32x16 acc[4];
    #pragma unroll
    for (int cb = 0; cb < 4; ++cb)
        #pragma unroll
        for (int r = 0; r < 16; ++r) acc[cb][r] = 0.f;
    f32x16 z16;
    #pragma unroll
    for (int r = 0; r < 16; ++r) z16[r] = 0.f;
    float s_run = 0.f;

    __syncthreads();   // obuf zeroed

    #pragma unroll 4
    for (int ch = 0; ch < 32; ++ch) {
        // K frags for the two 32-m halves of this chunk
        const unsigned char* kc = Kw + (size_t)ch * 2048;
        long kA0a = *(const long*)(kc);
        long kA1a = *(const long*)(kc + 16);
        long kA0b = *(const long*)(kc + 1024);
        long kA1b = *(const long*)(kc + 1024 + 16);

        // V B-frags for this wave's 4 c-blocks (issued early)
        const unsigned char* vc = Vw + (size_t)ch * 16384;
        Frag64 vb[4];
        #pragma unroll
        for (int cb = 0; cb < 4; ++cb)
            #pragma unroll
            for (int p = 0; p < 4; ++p)
                vb[cb].l[p] = *(const long*)(vc + (size_t)p * 4096 + cb * 512);

        // QK^T (swapped): lane lo = q, regs = m-local
        f32x16 s0 = __builtin_amdgcn_mfma_f32_32x32x16_fp8_fp8(kA0a, qf0, z16, 0, 0, 0);
        s0 = __builtin_amdgcn_mfma_f32_32x32x16_fp8_fp8(kA1a, qf1, s0, 0, 0, 0);
        f32x16 s1 = __builtin_amdgcn_mfma_f32_32x32x16_fp8_fp8(kA0b, qf0, z16, 0, 0, 0);
        s1 = __builtin_amdgcn_mfma_f32_32x32x16_fp8_fp8(kA1b, qf1, s1, 0, 0, 0);

        // exp2 -> fp8 -> in-register A-frag (no LDS)
        Frag64 pa;
        pa.l[0] = packhalf(s0, 0, s_run);
        pa.l[1] = packhalf(s0, 8, s_run);
        pa.l[2] = packhalf(s1, 0, s_run);
        pa.l[3] = packhalf(s1, 8, s_run);

        // PV: 4 independent K=64 MFMAs (acc rows = q, cols = c)
        __builtin_amdgcn_s_setprio(1);
        #pragma unroll
        for (int cb = 0; cb < 4; ++cb)
            acc[cb] = __builtin_amdgcn_mfma_scale_f32_32x32x64_f8f6f4(
                pa.v, vb[cb].v, acc[cb], 0, 0, 0, SC1, 0, SC1);
        __builtin_amdgcn_s_setprio(0);
    }

    // ---- cross-wave reduction: O partials into obuf via ds_add_f32 ----
    float* ob     = (float*)smem;
    float* red_sp = (float*)(smem + 37888);       // [2][32]
    float* red2p  = (float*)(smem + 38144);       // [32 q][4 w][2]

    #pragma unroll
    for (int cb = 0; cb < 4; ++cb) {
        #pragma unroll
        for (int r = 0; r < 16; ++r) {
            int qr = (r & 3) + 8 * (r >> 2) + 4 * hi;
            atomicAdd(&ob[qr * 256 + cw * 128 + 32 * cb + lo], acc[cb][r]);
        }
    }
    s_run += __shfl_xor(s_run, 32);
    if (cw == 0 && hi == 0) red_sp[mw * 32 + lo] = s_run;   // cw dup: write once
    __syncthreads();

    // ---- epilogue: residual + LayerNorm ----
    float stot = red_sp[lo] + red_sp[32 + lo];
    const float invs = 1.0f / stot;
    const float gamma = gamma_p[0];
    const int cL0 = 32 * wid + lo;
    const int cL1 = cL0 + 128;
    const __hip_bfloat16* XTb = XTg + ((size_t)b * NPIX + q0) * NCH;
    float rv[2][16];
    #pragma unroll
    for (int r = 0; r < 16; ++r) {
        int qr = (r & 3) + 8 * (r >> 2) + 4 * hi;
        float ir = bperm(qr, invs);
        float o0 = ob[qr * 256 + cL0];
        float o1 = ob[qr * 256 + cL1];
        float x0 = __bfloat162float(XTb[(size_t)qr * NCH + cL0]);
        float x1 = __bfloat162float(XTb[(size_t)qr * NCH + cL1]);
        rv[0][r] = gamma * (o0 * ir) + x0;
        rv[1][r] = gamma * (o1 * ir) + x1;
        float s1v = rv[0][r] + rv[1][r];
        float s2v = rv[0][r] * rv[0][r] + rv[1][r] * rv[1][r];
        #pragma unroll
        for (int off = 1; off < 32; off <<= 1) {
            s1v += __shfl_xor(s1v, off);
            s2v += __shfl_xor(s2v, off);
        }
        if (lo == 0) {
            red2p[qr * 8 + wid * 2]     = s1v;
            red2p[qr * 8 + wid * 2 + 1] = s2v;
        }
    }
    __syncthreads();   // red2 ready; obuf reads complete (ybuf overlays)
    float sA = 0.f, sB = 0.f;
    #pragma unroll
    for (int w = 0; w < 4; ++w) {
        sA += red2p[lo * 8 + w * 2];
        sB += red2p[lo * 8 + w * 2 + 1];
    }
    const float mean = sA * (1.f / 256.f);
    const float var  = sB * (1.f / 256.f) - mean * mean;
    const float rstd = rsqrtf(var + 1e-5f);
    const float lw0 = lnw[cL0], lb0 = lnb[cL0];
    const float lw1 = lnw[cL1], lb1 = lnb[cL1];
    float (*ybuf)[37] = (float(*)[37])smem;       // overlays obuf
    #pragma unroll
    for (int r = 0; r < 16; ++r) {
        int qr = (r & 3) + 8 * (r >> 2) + 4 * hi;
        float m  = bperm(qr, mean);
        float rr = bperm(qr, rstd);
        ybuf[cL0][qr] = (rv[0][r] - m) * rr * lw0 + lb0;
        ybuf[cL1][qr] = (rv[1][r] - m) * rr * lw1 + lb1;
    }
    __syncthreads();
    // store: thread t owns c-row t, 32 q's (128 B contiguous per row)
    float* dst = out + ((size_t)b * NCH + t) * NPIX + q0;
    #pragma unroll
    for (int j = 0; j < 8; ++j) {
        float4 v;
        v.x = ybuf[t][j * 4 + 0];
        v.y = ybuf[t][j * 4 + 1];
        v.z = ybuf[t][j * 4 + 2];
        v.w = ybuf[t][j * 4 + 3];
        *(float4*)(dst + j * 4) = v;
    }
}

// ---------------------------------------------------------------------------
extern "C" void kernel_launch(void* const* d_in, const int* in_sizes, int n_in,
                              void* d_out, int out_size, void* d_ws, size_t ws_size,
                              hipStream_t stream) {
    const float* x     = (const float*)d_in[0];
    const float* wq    = (const float*)d_in[1];
    const float* bq    = (const float*)d_in[2];
    const float* wk    = (const float*)d_in[3];
    const float* bk    = (const float*)d_in[4];
    const float* wv    = (const float*)d_in[5];
    const float* bv    = (const float*)d_in[6];
    const float* gamma = (const float*)d_in[7];
    const float* ln_w  = (const float*)d_in[8];
    const float* ln_b  = (const float*)d_in[9];
    float* out = (float*)d_out;

    const int B = 4;
    unsigned char* ws = (unsigned char*)d_ws;
    unsigned char*  Q8 = ws;                                   // 512 KB
    unsigned char*  K8 = ws + (512u << 10);                    // 512 KB
    unsigned char*  V8 = ws + (1u << 20);                      // 4 MB
    __hip_bfloat16* XT = (__hip_bfloat16*)(ws + (5u << 20));   // 8 MB
    __hip_bfloat16* Wc = (__hip_bfloat16*)(ws + (13u << 20));  // 160 KB
    float*          bc = (float*)(ws + (13u << 20) + 163840);  // 1.25 KB

    prep_kernel<<<dim3(1344), 256, 0, stream>>>(x, wq, bq, wk, bk, wv, bv,
                                                Wc, bc, XT);
    proj_kernel<<<dim3(32, 2, B), 256, 0, stream>>>(Wc, bc, XT, Q8, K8, V8);
    attn_kernel<<<dim3(128, B), 256, 0, stream>>>(Q8, K8, V8, XT, gamma,
                                                  ln_w, ln_b, out);
}